// Round 5
// baseline (46.938 us; speedup 1.0000x reference)
//
#include <hip/hip_runtime.h>

#define N 512
#define KAPPA2 0.1089f   // 0.33^2
#define GAMMA  1.0f
#define BETA   25.0f

// Load a 10-wide span s[0..9] covering px [x0-1 .. x0+8] for this lane's 8 px.
// Wave = full row: lane L owns px [8L, 8L+8). Edges come from neighbor lanes via
// shuffle; lane 0 / lane 63 get the Dirichlet zero boundary.
__device__ __forceinline__ void loadspan10(const float* __restrict__ p, int lane,
                                           float s[10]) {
    const float4 A = *reinterpret_cast<const float4*>(p);
    const float4 B = *reinterpret_cast<const float4*>(p + 4);
    s[1] = A.x; s[2] = A.y; s[3] = A.z; s[4] = A.w;
    s[5] = B.x; s[6] = B.y; s[7] = B.z; s[8] = B.w;
    const float lw = __shfl_up(B.w, 1, 64);
    const float rx = __shfl_down(A.x, 1, 64);
    s[0] = (lane == 0)  ? 0.0f : lw;
    s[9] = (lane == 63) ? 0.0f : rx;
}

__device__ __forceinline__ void zero10(float s[10]) {
    #pragma unroll
    for (int j = 0; j < 10; ++j) s[j] = 0.0f;
}

// state: [B=8, 9, 512, 512] f32. slices 0..6 = x_t, 7 = vx, 8 = vy.
// Fused: 1024 blocks = 8 batches (bid&7 -> XCD-pinned) x 128 four-row tiles.
// Each wave processes one full 512-px row across all 7 t-slices. Each block
// writes one partial; the LAST block (atomic counter) reduces all 1024
// partials and writes out[0..7]. Fixed reduction order -> deterministic.
__global__ __launch_bounds__(256) void phi_q_fused(const float* __restrict__ state,
                                                   float* __restrict__ ws,
                                                   float* __restrict__ out) {
    const int bid  = blockIdx.x;
    const int b    = bid & 7;        // batch == XCD (round-robin dispatch)
    const int yt   = bid >> 3;       // y-tile of 4 rows
    const int tid  = threadIdx.x;
    const int wid  = tid >> 6;       // wave -> row within tile
    const int lane = tid & 63;
    const int y    = yt * 4 + wid;

    const size_t slice  = (size_t)N * N;
    const float* base   = state + (size_t)b * 9 * slice;
    const size_t rowoff = (size_t)y * N + lane * 8;

    // Diffusion tensor for this row's 8 px (loaded once, reused for all 7 t).
    const float4 vxA = *reinterpret_cast<const float4*>(base + 7 * slice + rowoff);
    const float4 vxB = *reinterpret_cast<const float4*>(base + 7 * slice + rowoff + 4);
    const float4 vyA = *reinterpret_cast<const float4*>(base + 8 * slice + rowoff);
    const float4 vyB = *reinterpret_cast<const float4*>(base + 8 * slice + rowoff + 4);
    float H11[8], H12[8], H22[8];
    {
        const float vxs[8] = {vxA.x, vxA.y, vxA.z, vxA.w, vxB.x, vxB.y, vxB.z, vxB.w};
        const float vys[8] = {vyA.x, vyA.y, vyA.z, vyA.w, vyB.x, vyB.y, vyB.z, vyB.w};
        #pragma unroll
        for (int j = 0; j < 8; ++j) {
            H11[j] = GAMMA + BETA * vxs[j] * vxs[j];
            H12[j] = BETA * vxs[j] * vys[j];
            H22[j] = GAMMA + BETA * vys[j] * vys[j];
        }
    }

    const bool ym = (y > 0), yp = (y < N - 1);   // wave-uniform

    float q = 0.0f;
    float prevc[8];
    #pragma unroll
    for (int j = 0; j < 8; ++j) prevc[j] = 0.0f;

    #pragma unroll
    for (int t = 0; t < 7; ++t) {
        const float* u = base + (size_t)t * slice;
        float sm[10], sc[10], su[10];

        loadspan10(u + rowoff, lane, sc);
        if (ym) loadspan10(u + rowoff - N, lane, sm);
        else    zero10(sm);
        if (yp) loadspan10(u + rowoff + N, lane, su);
        else    zero10(su);

        #pragma unroll
        for (int j = 0; j < 8; ++j) {
            const float c   = sc[j + 1];
            const float uxx = sc[j] + sc[j + 2] - 2.0f * c;
            const float uyy = sm[j + 1] + su[j + 1] - 2.0f * c;
            const float uxy = 0.25f * (su[j + 2] - su[j] - sm[j + 2] + sm[j]);
            const float div = H11[j] * uxx + 2.0f * H12[j] * uxy + H22[j] * uyy;
            const float Ax  = KAPPA2 * c - div;
            const float Mx  = c + Ax;   // DT = 1

            if (t == 0) {
                q += Ax * Ax + 1.05f * c * c;
            } else {
                q += Mx * Mx;
                if (t < 6) q += c * c;
                q -= 2.0f * prevc[j] * Mx;
            }
            prevc[j] = c;
        }
    }

    // wave reduce + block reduce -> one partial per block
    #pragma unroll
    for (int off = 32; off > 0; off >>= 1)
        q += __shfl_down(q, off, 64);

    __shared__ float sred[4];
    __shared__ int s_last;
    if (lane == 0) sred[wid] = q;
    __syncthreads();
    if (tid == 0) {
        ws[bid] = sred[0] + sred[1] + sred[2] + sred[3];
        __threadfence();                                     // release partial
        unsigned old = atomicAdd((unsigned int*)(ws + 1024), 1u);
        s_last = (old == 1023u) ? 1 : 0;
    }
    __syncthreads();

    if (s_last) {
        __threadfence();                                     // acquire partials
        // 256 threads x 4 partials each; index mod 8 == batch == tid&7.
        float v = ws[tid] + ws[tid + 256] + ws[tid + 512] + ws[tid + 768];
        v += __shfl_down(v, 32, 64);
        v += __shfl_down(v, 16, 64);
        v += __shfl_down(v, 8, 64);
        __shared__ float sb[4][8];
        if (lane < 8) sb[wid][lane] = v;
        __syncthreads();
        if (tid < 8) out[tid] = sb[0][tid] + sb[1][tid] + sb[2][tid] + sb[3][tid];
    }
}

extern "C" void kernel_launch(void* const* d_in, const int* in_sizes, int n_in,
                              void* d_out, int out_size, void* d_ws, size_t ws_size,
                              hipStream_t stream) {
    const float* state = (const float*)d_in[0];
    float* out = (float*)d_out;
    float* ws  = (float*)d_ws;

    // zero the completion counter (ws[1024]) each call; capture-safe.
    hipMemsetAsync(ws + 1024, 0, sizeof(unsigned int), stream);
    phi_q_fused<<<1024, 256, 0, stream>>>(state, ws, out);
}

// Round 6
// 33.763 us; speedup vs baseline: 1.3902x; 1.3902x over previous
//
#include <hip/hip_runtime.h>

#define N 512
#define KAPPA2 0.1089f   // 0.33^2
#define GAMMA  1.0f
#define BETA   25.0f

// Wave = half-row: lane L owns px [x0, x0+4), x0 = half*256 + L*4.
// Span s[0..5] covers px [x0-1 .. x0+4]. Interior edges via shuffle; the
// half-row seam (px 255/256) needs one exec-masked scalar load; grid edge = 0.
__device__ __forceinline__ void span6(const float* __restrict__ p, int lane,
                                      bool seamL, bool seamR, float s[6]) {
    const float4 v = *reinterpret_cast<const float4*>(p);
    s[1] = v.x; s[2] = v.y; s[3] = v.z; s[4] = v.w;
    float el = __shfl_up(v.w, 1, 64);    // left neighbor's last px
    float er = __shfl_down(v.x, 1, 64);  // right neighbor's first px
    if (seamL) el = p[-1]; else if (lane == 0)  el = 0.0f;
    if (seamR) er = p[4];  else if (lane == 63) er = 0.0f;
    s[0] = el; s[5] = er;
}

__device__ __forceinline__ void zero6(float s[6]) {
    #pragma unroll
    for (int j = 0; j < 6; ++j) s[j] = 0.0f;
}

// state: [B=8, 9, 512, 512] f32. slices 0..6 = x_t, 7 = vx, 8 = vy.
// Stage 1: 2048 blocks = 8 batches (bid&7 -> XCD-pinned) x 256 row-pairs.
// 4 waves/block: wave = (row within pair, half of row). Partial per block.
__global__ __launch_bounds__(256) void phi_q_stage1(const float* __restrict__ state,
                                                    float* __restrict__ ws) {
    const int bid  = blockIdx.x;
    const int b    = bid & 7;        // batch == XCD (round-robin dispatch)
    const int yp2  = bid >> 3;       // row pair
    const int tid  = threadIdx.x;
    const int w    = tid >> 6;
    const int lane = tid & 63;
    const int y    = yp2 * 2 + (w >> 1);
    const int half = w & 1;
    const int x0   = half * 256 + lane * 4;

    const size_t slice = (size_t)N * N;
    const float* base  = state + (size_t)b * 9 * slice;
    const size_t idx   = (size_t)y * N + x0;

    const bool ym = (y > 0), yp = (y < N - 1);             // wave-uniform
    const bool seamL = (half == 1) && (lane == 0);         // px 255 from left half
    const bool seamR = (half == 0) && (lane == 63);        // px 256 from right half

    // Diffusion tensor for this lane's 4 px (loaded once, reused for all 7 t).
    const float4 vx4 = *reinterpret_cast<const float4*>(base + 7 * slice + idx);
    const float4 vy4 = *reinterpret_cast<const float4*>(base + 8 * slice + idx);
    float H11[4], H12[4], H22[4];
    {
        const float vxs[4] = {vx4.x, vx4.y, vx4.z, vx4.w};
        const float vys[4] = {vy4.x, vy4.y, vy4.z, vy4.w};
        #pragma unroll
        for (int j = 0; j < 4; ++j) {
            H11[j] = GAMMA + BETA * vxs[j] * vxs[j];
            H12[j] = BETA * vxs[j] * vys[j];
            H22[j] = GAMMA + BETA * vys[j] * vys[j];
        }
    }

    float q = 0.0f;
    float prevc[4] = {0.0f, 0.0f, 0.0f, 0.0f};

    #pragma unroll
    for (int t = 0; t < 7; ++t) {
        const float* u = base + (size_t)t * slice;
        float sm[6], sc[6], su[6];

        span6(u + idx, lane, seamL, seamR, sc);
        if (ym) span6(u + idx - N, lane, seamL, seamR, sm);
        else    zero6(sm);
        if (yp) span6(u + idx + N, lane, seamL, seamR, su);
        else    zero6(su);

        #pragma unroll
        for (int j = 0; j < 4; ++j) {
            const float c   = sc[j + 1];
            const float uxx = sc[j] + sc[j + 2] - 2.0f * c;
            const float uyy = sm[j + 1] + su[j + 1] - 2.0f * c;
            const float uxy = 0.25f * (su[j + 2] - su[j] - sm[j + 2] + sm[j]);
            const float div = H11[j] * uxx + 2.0f * H12[j] * uxy + H22[j] * uyy;
            const float Ax  = KAPPA2 * c - div;
            const float Mx  = c + Ax;   // DT = 1

            if (t == 0) {
                q += Ax * Ax + 1.05f * c * c;
            } else {
                q += Mx * Mx;
                if (t < 6) q += c * c;
                q -= 2.0f * prevc[j] * Mx;
            }
            prevc[j] = c;
        }
    }

    // wave reduce + block reduce -> one partial per block
    #pragma unroll
    for (int off = 32; off > 0; off >>= 1)
        q += __shfl_down(q, off, 64);

    __shared__ float sred[4];
    if (lane == 0) sred[w] = q;
    __syncthreads();
    if (tid == 0) ws[bid] = sred[0] + sred[1] + sred[2] + sred[3];
}

// Stage 2: 8 blocks; block b sums the 256 partials of batch b (ws[b + 8k]).
__global__ __launch_bounds__(256) void phi_q_stage2(const float* __restrict__ ws,
                                                    float* __restrict__ out) {
    const int b = blockIdx.x;
    float v = ws[b + 8 * threadIdx.x];
    #pragma unroll
    for (int off = 32; off > 0; off >>= 1)
        v += __shfl_down(v, off, 64);

    __shared__ float sred[4];
    const int lane = threadIdx.x & 63;
    const int wid  = threadIdx.x >> 6;
    if (lane == 0) sred[wid] = v;
    __syncthreads();
    if (threadIdx.x == 0) out[b] = sred[0] + sred[1] + sred[2] + sred[3];
}

extern "C" void kernel_launch(void* const* d_in, const int* in_sizes, int n_in,
                              void* d_out, int out_size, void* d_ws, size_t ws_size,
                              hipStream_t stream) {
    const float* state = (const float*)d_in[0];
    float* out = (float*)d_out;
    float* ws  = (float*)d_ws;

    phi_q_stage1<<<2048, 256, 0, stream>>>(state, ws);
    phi_q_stage2<<<8, 256, 0, stream>>>(ws, out);
}

// Round 7
// 26.087 us; speedup vs baseline: 1.7993x; 1.2943x over previous
//
#include <hip/hip_runtime.h>

#define N 512
#define KAPPA2 0.1089f   // 0.33^2
#define GAMMA  1.0f
#define BETA   25.0f

// Wave = full row: lane L owns px [8L, 8L+8). Span s[0..9] covers [8L-1, 8L+8].
// Edges via shuffle; lane 0 / 63 get the Dirichlet zero boundary.
__device__ __forceinline__ void loadspan10(const float* __restrict__ p, int lane,
                                           float s[10]) {
    const float4 A = *reinterpret_cast<const float4*>(p);
    const float4 B = *reinterpret_cast<const float4*>(p + 4);
    s[1] = A.x; s[2] = A.y; s[3] = A.z; s[4] = A.w;
    s[5] = B.x; s[6] = B.y; s[7] = B.z; s[8] = B.w;
    const float lw = __shfl_up(B.w, 1, 64);
    const float rx = __shfl_down(A.x, 1, 64);
    s[0] = (lane == 0)  ? 0.0f : lw;
    s[9] = (lane == 63) ? 0.0f : rx;
}

__device__ __forceinline__ void zero10(float s[10]) {
    #pragma unroll
    for (int j = 0; j < 10; ++j) s[j] = 0.0f;
}

// state: [B=8, 9, 512, 512] f32. slices 0..6 = x_t, 7 = vx, 8 = vy.
// q decomposition: f_0 = |Ax0|^2 + 1.05|x0|^2;
//                  f_t = |Mx_t|^2 - 2 x_{t-1}.Mx_t + [t<6]|x_t|^2  (t=1..6)
// Stage 1: 4096 blocks = (y, b), b = bid&7 (XCD-pinned). 7 waves/block,
// wave w computes f_w for its row. Short independent load chains per wave.
__global__ __launch_bounds__(448, 6) void phi_q_stage1(const float* __restrict__ state,
                                                       float* __restrict__ ws) {
    const int bid  = blockIdx.x;     // 512*8
    const int b    = bid & 7;
    const int y    = bid >> 3;
    const int tid  = threadIdx.x;
    const int w    = tid >> 6;       // 0..6 == t
    const int lane = tid & 63;

    const size_t slice  = (size_t)N * N;
    const float* base   = state + (size_t)b * 9 * slice;
    const size_t rowoff = (size_t)y * N + lane * 8;

    const bool ym = (y > 0), yp = (y < N - 1);   // wave-uniform

    // vx, vy for this row's 8 px (H expanded in the FMA chain to save VGPRs)
    const float4 vxA = *reinterpret_cast<const float4*>(base + 7 * slice + rowoff);
    const float4 vxB = *reinterpret_cast<const float4*>(base + 7 * slice + rowoff + 4);
    const float4 vyA = *reinterpret_cast<const float4*>(base + 8 * slice + rowoff);
    const float4 vyB = *reinterpret_cast<const float4*>(base + 8 * slice + rowoff + 4);
    const float vxs[8] = {vxA.x, vxA.y, vxA.z, vxA.w, vxB.x, vxB.y, vxB.z, vxB.w};
    const float vys[8] = {vyA.x, vyA.y, vyA.z, vyA.w, vyB.x, vyB.y, vyB.z, vyB.w};

    // Stencil spans of slice w at rows y-1, y, y+1.
    const float* u = base + (size_t)w * slice;
    float sm[10], sc[10], su[10];
    loadspan10(u + rowoff, lane, sc);
    if (ym) loadspan10(u + rowoff - N, lane, sm);
    else    zero10(sm);
    if (yp) loadspan10(u + rowoff + N, lane, su);
    else    zero10(su);

    // x_{t-1} center row (cross term), only for w >= 1.
    float xp8[8];
    if (w > 0) {
        const float* up = u - slice;
        const float4 XA = *reinterpret_cast<const float4*>(up + rowoff);
        const float4 XB = *reinterpret_cast<const float4*>(up + rowoff + 4);
        xp8[0] = XA.x; xp8[1] = XA.y; xp8[2] = XA.z; xp8[3] = XA.w;
        xp8[4] = XB.x; xp8[5] = XB.y; xp8[6] = XB.z; xp8[7] = XB.w;
    } else {
        #pragma unroll
        for (int j = 0; j < 8; ++j) xp8[j] = 0.0f;
    }

    float q = 0.0f;
    #pragma unroll
    for (int j = 0; j < 8; ++j) {
        const float c   = sc[j + 1];
        const float uxx = sc[j] + sc[j + 2] - 2.0f * c;
        const float uyy = sm[j + 1] + su[j + 1] - 2.0f * c;
        const float uxy = 0.25f * (su[j + 2] - su[j] - sm[j + 2] + sm[j]);
        const float vx = vxs[j], vy = vys[j];
        const float div = (GAMMA + BETA * vx * vx) * uxx
                        + (2.0f * BETA * vx * vy) * uxy
                        + (GAMMA + BETA * vy * vy) * uyy;
        const float Ax  = KAPPA2 * c - div;
        if (w == 0) {                      // wave-uniform branch
            q += Ax * Ax + 1.05f * c * c;
        } else {
            const float Mx = c + Ax;       // DT = 1
            q += Mx * Mx - 2.0f * xp8[j] * Mx;
            if (w < 6) q += c * c;         // nx for t = 1..5
        }
    }

    // wave reduce + block reduce -> one partial per block
    #pragma unroll
    for (int off = 32; off > 0; off >>= 1)
        q += __shfl_down(q, off, 64);

    __shared__ float sred[7];
    if (lane == 0) sred[w] = q;
    __syncthreads();
    if (tid == 0) {
        ws[bid] = sred[0] + sred[1] + sred[2] + sred[3]
                + sred[4] + sred[5] + sred[6];
    }
}

// Stage 2: 8 blocks; block b sums the 512 partials of batch b (ws[b + 8k]).
__global__ __launch_bounds__(256) void phi_q_stage2(const float* __restrict__ ws,
                                                    float* __restrict__ out) {
    const int b = blockIdx.x;
    float v = ws[b + 8 * threadIdx.x] + ws[b + 8 * (threadIdx.x + 256)];
    #pragma unroll
    for (int off = 32; off > 0; off >>= 1)
        v += __shfl_down(v, off, 64);

    __shared__ float sred[4];
    const int lane = threadIdx.x & 63;
    const int wid  = threadIdx.x >> 6;
    if (lane == 0) sred[wid] = v;
    __syncthreads();
    if (threadIdx.x == 0) out[b] = sred[0] + sred[1] + sred[2] + sred[3];
}

extern "C" void kernel_launch(void* const* d_in, const int* in_sizes, int n_in,
                              void* d_out, int out_size, void* d_ws, size_t ws_size,
                              hipStream_t stream) {
    const float* state = (const float*)d_in[0];
    float* out = (float*)d_out;
    float* ws  = (float*)d_ws;

    phi_q_stage1<<<4096, 448, 0, stream>>>(state, ws);
    phi_q_stage2<<<8, 256, 0, stream>>>(ws, out);
}

// Round 8
// 24.542 us; speedup vs baseline: 1.9125x; 1.0629x over previous
//
#include <hip/hip_runtime.h>

#define N 512
#define KAPPA2 0.1089f   // 0.33^2
#define GAMMA  1.0f
#define BETA   25.0f

// Wave = full row: lane L owns px [8L, 8L+8). Span s[0..9] covers [8L-1, 8L+8].
// Edges via shuffle; lane 0 / 63 get the Dirichlet zero boundary.
__device__ __forceinline__ void loadspan10(const float* __restrict__ p, int lane,
                                           float s[10]) {
    const float4 A = *reinterpret_cast<const float4*>(p);
    const float4 B = *reinterpret_cast<const float4*>(p + 4);
    s[1] = A.x; s[2] = A.y; s[3] = A.z; s[4] = A.w;
    s[5] = B.x; s[6] = B.y; s[7] = B.z; s[8] = B.w;
    const float lw = __shfl_up(B.w, 1, 64);
    const float rx = __shfl_down(A.x, 1, 64);
    s[0] = (lane == 0)  ? 0.0f : lw;
    s[9] = (lane == 63) ? 0.0f : rx;
}

__device__ __forceinline__ void zero10(float s[10]) {
    #pragma unroll
    for (int j = 0; j < 10; ++j) s[j] = 0.0f;
}

// state: [B=8, 9, 512, 512] f32. slices 0..6 = x_t, 7 = vx, 8 = vy.
// q decomposition: f_0 = |Ax0|^2 + 1.05|x0|^2;
//                  f_t = |Mx_t|^2 - 2 x_{t-1}.Mx_t + [t<6]|x_t|^2  (t=1..6)
// Stage 1: one wave per (b, y, t). bid = (y*7+t)*8 + b: batch pinned to one
// XCD by the default %8 round-robin; y-neighbor waves (row reuse) adjacent.
// 1-wave blocks: no LDS, no barrier, wave-granular packing; VGPR<=72 -> 7/SIMD.
__global__ __launch_bounds__(64, 7) void phi_q_stage1(const float* __restrict__ state,
                                                      float* __restrict__ ws) {
    const int bid  = blockIdx.x;         // 28672 = 512*7*8
    const int b    = bid & 7;
    const int yt   = bid >> 3;           // y*7 + t
    const int y    = yt / 7;             // scalar magic-div (uniform)
    const int t    = yt - y * 7;
    const int lane = threadIdx.x;

    const size_t slice  = (size_t)N * N;
    const float* base   = state + (size_t)b * 9 * slice;
    const size_t rowoff = (size_t)y * N + lane * 8;

    const bool ym = (y > 0), yp = (y < N - 1);   // wave-uniform

    // Deep-chain loads first: stencil spans of slice t at rows y-1, y, y+1.
    const float* u = base + (size_t)t * slice;
    float sm[10], sc[10], su[10];
    loadspan10(u + rowoff, lane, sc);
    if (ym) loadspan10(u + rowoff - N, lane, sm);
    else    zero10(sm);
    if (yp) loadspan10(u + rowoff + N, lane, su);
    else    zero10(su);

    // Then the straight loads: vx, vy (H expanded in FMAs), x_{t-1} row.
    const float4 vxA = *reinterpret_cast<const float4*>(base + 7 * slice + rowoff);
    const float4 vxB = *reinterpret_cast<const float4*>(base + 7 * slice + rowoff + 4);
    const float4 vyA = *reinterpret_cast<const float4*>(base + 8 * slice + rowoff);
    const float4 vyB = *reinterpret_cast<const float4*>(base + 8 * slice + rowoff + 4);
    const float vxs[8] = {vxA.x, vxA.y, vxA.z, vxA.w, vxB.x, vxB.y, vxB.z, vxB.w};
    const float vys[8] = {vyA.x, vyA.y, vyA.z, vyA.w, vyB.x, vyB.y, vyB.z, vyB.w};

    float xp8[8];
    if (t > 0) {                          // wave-uniform
        const float* up = u - slice;
        const float4 XA = *reinterpret_cast<const float4*>(up + rowoff);
        const float4 XB = *reinterpret_cast<const float4*>(up + rowoff + 4);
        xp8[0] = XA.x; xp8[1] = XA.y; xp8[2] = XA.z; xp8[3] = XA.w;
        xp8[4] = XB.x; xp8[5] = XB.y; xp8[6] = XB.z; xp8[7] = XB.w;
    } else {
        #pragma unroll
        for (int j = 0; j < 8; ++j) xp8[j] = 0.0f;
    }

    float q = 0.0f;
    #pragma unroll
    for (int j = 0; j < 8; ++j) {
        const float c   = sc[j + 1];
        const float uxx = sc[j] + sc[j + 2] - 2.0f * c;
        const float uyy = sm[j + 1] + su[j + 1] - 2.0f * c;
        const float uxy = 0.25f * (su[j + 2] - su[j] - sm[j + 2] + sm[j]);
        const float vx = vxs[j], vy = vys[j];
        const float div = (GAMMA + BETA * vx * vx) * uxx
                        + (2.0f * BETA * vx * vy) * uxy
                        + (GAMMA + BETA * vy * vy) * uyy;
        const float Ax  = KAPPA2 * c - div;
        if (t == 0) {                      // wave-uniform branch
            q += Ax * Ax + 1.05f * c * c;
        } else {
            const float Mx = c + Ax;       // DT = 1
            q += Mx * Mx - 2.0f * xp8[j] * Mx;
            if (t < 6) q += c * c;         // nx for t = 1..5
        }
    }

    // wave reduce -> one partial per wave, transposed layout for stage 2.
    #pragma unroll
    for (int off = 32; off > 0; off >>= 1)
        q += __shfl_down(q, off, 64);

    if (lane == 0) ws[b * 3584 + yt] = q;   // 3584 = 512*7
}

// Stage 2: 8 blocks; block b sums its contiguous 3584 partials (14 per thread,
// coalesced), then block-reduces.
__global__ __launch_bounds__(256) void phi_q_stage2(const float* __restrict__ ws,
                                                    float* __restrict__ out) {
    const int b = blockIdx.x;
    const float* p = ws + b * 3584;
    float v = 0.0f;
    #pragma unroll
    for (int k = 0; k < 14; ++k)
        v += p[k * 256 + threadIdx.x];

    #pragma unroll
    for (int off = 32; off > 0; off >>= 1)
        v += __shfl_down(v, off, 64);

    __shared__ float sred[4];
    const int lane = threadIdx.x & 63;
    const int wid  = threadIdx.x >> 6;
    if (lane == 0) sred[wid] = v;
    __syncthreads();
    if (threadIdx.x == 0) out[b] = sred[0] + sred[1] + sred[2] + sred[3];
}

extern "C" void kernel_launch(void* const* d_in, const int* in_sizes, int n_in,
                              void* d_out, int out_size, void* d_ws, size_t ws_size,
                              hipStream_t stream) {
    const float* state = (const float*)d_in[0];
    float* out = (float*)d_out;
    float* ws  = (float*)d_ws;

    phi_q_stage1<<<28672, 64, 0, stream>>>(state, ws);
    phi_q_stage2<<<8, 256, 0, stream>>>(ws, out);
}